// Round 1
// baseline (1539.689 us; speedup 1.0000x reference)
//
#include <hip/hip_runtime.h>
#include <math.h>

#define NH   16      // num heads
#define NKV  4       // kv heads
#define QKB  64      // q/k bits
#define VBV  64      // value bits
#define HID  2048
#define BAT  2
#define SEQ  2048
#define REP  (NH / NKV)

// ---------------------------------------------------------------------------
// Generic tiled fp32 GEMM with fused activation epilogue.
// C[M,N] = act(A[M,K] @ Bm[K,N]);  ACT: 0=none, 1=tanh, 2=sigmoid
// BM=BN=64, BK=16, 256 threads, 4x4 microtile per thread.
// Requires M%64==0, N%64==0, K%16==0 (true for all our shapes).
// ---------------------------------------------------------------------------
template <int ACT>
__global__ __launch_bounds__(256) void gemm_act(const float* __restrict__ A,
                                                const float* __restrict__ Bm,
                                                float* __restrict__ C,
                                                int M, int N, int K)
{
    __shared__ float As[16][64];   // [k][m] (transposed for b128 compute reads)
    __shared__ float Bs[16][64];   // [k][n]

    const int tid = threadIdx.x;
    const int m0 = blockIdx.y * 64;
    const int n0 = blockIdx.x * 64;
    const int tx = tid & 15;       // n-group
    const int ty = tid >> 4;       // m-group

    // loader indices
    const int am = tid >> 2;            // 0..63 A row in tile
    const int ak = (tid & 3) * 4;       // k offset (float4)
    const int bk = tid >> 4;            // 0..15 B row in tile
    const int bn = (tid & 15) * 4;      // n offset (float4)

    float c[4][4] = {};

    for (int k0 = 0; k0 < K; k0 += 16) {
        float4 av = *(const float4*)(A + (size_t)(m0 + am) * K + k0 + ak);
        float4 bv = *(const float4*)(Bm + (size_t)(k0 + bk) * N + n0 + bn);
        __syncthreads();
        As[ak + 0][am] = av.x;
        As[ak + 1][am] = av.y;
        As[ak + 2][am] = av.z;
        As[ak + 3][am] = av.w;
        *(float4*)&Bs[bk][bn] = bv;
        __syncthreads();
#pragma unroll
        for (int kk = 0; kk < 16; ++kk) {
            float4 a = *(const float4*)&As[kk][ty * 4];
            float4 b = *(const float4*)&Bs[kk][tx * 4];
            c[0][0] += a.x * b.x; c[0][1] += a.x * b.y; c[0][2] += a.x * b.z; c[0][3] += a.x * b.w;
            c[1][0] += a.y * b.x; c[1][1] += a.y * b.y; c[1][2] += a.y * b.z; c[1][3] += a.y * b.w;
            c[2][0] += a.z * b.x; c[2][1] += a.z * b.y; c[2][2] += a.z * b.z; c[2][3] += a.z * b.w;
            c[3][0] += a.w * b.x; c[3][1] += a.w * b.y; c[3][2] += a.w * b.z; c[3][3] += a.w * b.w;
        }
    }

#pragma unroll
    for (int i = 0; i < 4; ++i) {
        float4 v;
        float* vp = (float*)&v;
#pragma unroll
        for (int j = 0; j < 4; ++j) {
            float x = c[i][j];
            if (ACT == 1) x = tanhf(x);
            else if (ACT == 2) x = 1.0f / (1.0f + expf(-x));
            vp[j] = x;
        }
        *(float4*)(C + (size_t)(m0 + ty * 4 + i) * N + n0 + tx * 4) = v;
    }
}

// ---------------------------------------------------------------------------
// Flash-style causal attention over pre-activated qb=tanh(xq), kb=tanh(xk),
// vp=sigmoid(xv). One block = (b, h, 64-query tile), 256 threads.
// Thread (i = tid/4, sub = tid%4): row i, 16 k-columns / 16 v-columns.
// Epilogue fuses out_bits = emb0 + ctx*(emb1-emb0).
// ---------------------------------------------------------------------------
__global__ __launch_bounds__(256) void rosa_attn(const float* __restrict__ qb,
                                                 const float* __restrict__ kb,
                                                 const float* __restrict__ vpr,
                                                 const int* __restrict__ amask,
                                                 const float* __restrict__ emb0,
                                                 const float* __restrict__ emb1,
                                                 float* __restrict__ outbits)
{
    __shared__ float Qs[64][65];   // [i][d]
    __shared__ float Kt[64][68];   // [d][j]  (transposed; 68 keeps rows 16B-aligned)
    __shared__ float Vs[64][68];   // [j][v]
    __shared__ float Ps[64][65];   // [i][j]
    __shared__ int   Ms[64];

    const int qt = blockIdx.x;     // query tile 0..31
    const int h  = blockIdx.y;     // head
    const int b  = blockIdx.z;     // batch
    const int g  = h / REP;        // kv head
    const int tid = threadIdx.x;
    const int q0 = qt * 64;

    // stage Q tile (consecutive tid -> consecutive d: coalesced)
    for (int idx = tid; idx < 64 * 64; idx += 256) {
        int i = idx >> 6, d = idx & 63;
        Qs[i][d] = qb[(((size_t)b * SEQ + q0 + i) * NH + h) * QKB + d];
    }

    const int i   = tid >> 2;      // row 0..63
    const int sub = tid & 3;       // column group

    float m_i = -INFINITY, l_i = 0.0f;
    float acc[16];
#pragma unroll
    for (int t = 0; t < 16; ++t) acc[t] = 0.0f;

    const float inv = 1.0f / (float)QKB;
    const int nkt = qt + 1;        // causal: only tiles with k0 <= q0

    for (int kt = 0; kt < nkt; ++kt) {
        const int k0 = kt * 64;
        __syncthreads();           // previous tile's LDS reads done
        for (int idx = tid; idx < 64 * 64; idx += 256) {
            int j = idx >> 6, d = idx & 63;
            Kt[d][j] = kb[(((size_t)b * SEQ + k0 + j) * NKV + g) * QKB + d];
        }
        for (int idx = tid; idx < 64 * 64; idx += 256) {
            int j = idx >> 6, v = idx & 63;
            Vs[j][v] = vpr[(((size_t)b * SEQ + k0 + j) * NKV + g) * VBV + v];
        }
        if (tid < 64) Ms[tid] = amask[b * SEQ + k0 + tid];
        __syncthreads();

        // scores: s[jj] = sum_d Q[i][d] * K[k0+sub*16+jj][d]
        float s[16];
#pragma unroll
        for (int jj = 0; jj < 16; ++jj) s[jj] = 0.0f;
        for (int d = 0; d < 64; ++d) {
            float qd = Qs[i][d];
            const float4* kr = (const float4*)&Kt[d][sub * 16];
#pragma unroll
            for (int jv = 0; jv < 4; ++jv) {
                float4 k4 = kr[jv];
                s[jv * 4 + 0] += qd * k4.x;
                s[jv * 4 + 1] += qd * k4.y;
                s[jv * 4 + 2] += qd * k4.z;
                s[jv * 4 + 3] += qd * k4.w;
            }
        }

        // scale + causal/padding mask + row max
        float mx = -INFINITY;
#pragma unroll
        for (int jj = 0; jj < 16; ++jj) {
            int j = sub * 16 + jj;
            bool valid = ((k0 + j) <= (q0 + i)) && (Ms[j] != 0);
            s[jj] = valid ? s[jj] * inv : -INFINITY;
            mx = fmaxf(mx, s[jj]);
        }
        mx = fmaxf(mx, __shfl_xor(mx, 1));
        mx = fmaxf(mx, __shfl_xor(mx, 2));
        float m_new = fmaxf(m_i, mx);

        float alpha = expf(m_i - m_new);
        m_i = m_new;

        float ps = 0.0f;
#pragma unroll
        for (int jj = 0; jj < 16; ++jj) {
            float p = expf(s[jj] - m_new);   // -INF -> 0
            ps += p;
            Ps[i][sub * 16 + jj] = p;
        }
        ps += __shfl_xor(ps, 1);
        ps += __shfl_xor(ps, 2);
        l_i = l_i * alpha + ps;

#pragma unroll
        for (int t = 0; t < 16; ++t) acc[t] *= alpha;

        __syncthreads();           // Ps visible block-wide (conservative)

        // ctx accumulate: acc[v] += sum_j P[i][j] * V[j][sub*16+v]
        const float* pr = Ps[i];
        for (int j = 0; j < 64; ++j) {
            float pj = pr[j];
            const float4* vr = (const float4*)&Vs[j][sub * 16];
#pragma unroll
            for (int vv = 0; vv < 4; ++vv) {
                float4 v4 = vr[vv];
                acc[vv * 4 + 0] += pj * v4.x;
                acc[vv * 4 + 1] += pj * v4.y;
                acc[vv * 4 + 2] += pj * v4.z;
                acc[vv * 4 + 3] += pj * v4.w;
            }
        }
    }

    // epilogue: ctx = acc/l ; out_bits = e0 + ctx*(e1-e0)
    float invl = 1.0f / l_i;
    float* dst = outbits + (((size_t)b * SEQ + q0 + i) * NH + h) * VBV + sub * 16;
#pragma unroll
    for (int vv = 0; vv < 4; ++vv) {
        float4 o;
        float* op = (float*)&o;
#pragma unroll
        for (int t = 0; t < 4; ++t) {
            int v = sub * 16 + vv * 4 + t;
            float ctxv = acc[vv * 4 + t] * invl;
            float e0 = emb0[h * VBV + v];
            float e1 = emb1[h * VBV + v];
            op[t] = e0 + ctxv * (e1 - e0);
        }
        *(float4*)(dst + vv * 4) = o;
    }
}

// ---------------------------------------------------------------------------
extern "C" void kernel_launch(void* const* d_in, const int* in_sizes, int n_in,
                              void* d_out, int out_size, void* d_ws, size_t ws_size,
                              hipStream_t stream)
{
    const float* x     = (const float*)d_in[0];
    const int*   amask = (const int*)d_in[1];
    const float* Wq    = (const float*)d_in[2];
    const float* Wk    = (const float*)d_in[3];
    const float* Wv    = (const float*)d_in[4];
    const float* Wo    = (const float*)d_in[5];
    const float* emb0  = (const float*)d_in[6];
    const float* emb1  = (const float*)d_in[7];
    float* out = (float*)d_out;

    float* ws = (float*)d_ws;
    float* qb = ws;                                        // [B,S,H,QKB]  4M floats
    float* kb = qb + (size_t)BAT * SEQ * NH * QKB;         // [B,S,KV,QKB] 1M
    float* vp = kb + (size_t)BAT * SEQ * NKV * QKB;        // [B,S,KV,VB]  1M
    float* ob = vp + (size_t)BAT * SEQ * NKV * VBV;        // [B,S,H,VB]   4M

    const int M = BAT * SEQ;   // 4096

    gemm_act<1><<<dim3((NH * QKB) / 64, M / 64), 256, 0, stream>>>(x, Wq, qb, M, NH * QKB, HID);
    gemm_act<1><<<dim3((NKV * QKB) / 64, M / 64), 256, 0, stream>>>(x, Wk, kb, M, NKV * QKB, HID);
    gemm_act<2><<<dim3((NKV * VBV) / 64, M / 64), 256, 0, stream>>>(x, Wv, vp, M, NKV * VBV, HID);

    rosa_attn<<<dim3(SEQ / 64, NH, BAT), 256, 0, stream>>>(qb, kb, vp, amask, emb0, emb1, ob);

    gemm_act<0><<<dim3(HID / 64, M / 64), 256, 0, stream>>>(ob, Wo, out, M, HID, NH * VBV);
}

// Round 2
// 295.433 us; speedup vs baseline: 5.2116x; 5.2116x over previous
//
#include <hip/hip_runtime.h>
#include <math.h>

typedef short bf16x8 __attribute__((ext_vector_type(8)));
typedef float f32x4 __attribute__((ext_vector_type(4)));

#define MFMA_BF16(A,B,C) __builtin_amdgcn_mfma_f32_16x16x32_bf16(A,B,C,0,0,0)

__device__ __forceinline__ unsigned short f2b(float x) {
    union { float f; unsigned int u; } v; v.f = x;
    unsigned int r = v.u + 0x7FFFu + ((v.u >> 16) & 1u);
    return (unsigned short)(r >> 16);
}

// ---------------------------------------------------------------------------
// fp32 -> bf16 convert (flat)
// ---------------------------------------------------------------------------
__global__ __launch_bounds__(256) void conv_bf16(const float* __restrict__ s,
                                                 unsigned short* __restrict__ d, int n)
{
    int i = blockIdx.x * blockDim.x + threadIdx.x;
    int stride = gridDim.x * blockDim.x;
    for (int idx = i * 4; idx < n; idx += stride * 4) {
        float4 v = *(const float4*)(s + idx);
        ushort4 o;
        o.x = f2b(v.x); o.y = f2b(v.y); o.z = f2b(v.z); o.w = f2b(v.w);
        *(ushort4*)(d + idx) = o;
    }
}

// ---------------------------------------------------------------------------
// fp32 [R][C] -> bf16 transposed [C][R] (dst pitch = R). R,C multiples of 32.
// ---------------------------------------------------------------------------
__global__ __launch_bounds__(256) void transp_conv(const float* __restrict__ src, int R, int C,
                                                   unsigned short* __restrict__ dst, int pitch)
{
    __shared__ float t[32][33];
    const int tx = threadIdx.x, ty = threadIdx.y;   // (32,8)
    const int c = blockIdx.x * 32 + tx;
    const int r0 = blockIdx.y * 32;
#pragma unroll
    for (int i = 0; i < 4; ++i)
        t[ty + i * 8][tx] = src[(size_t)(r0 + ty + i * 8) * C + c];
    __syncthreads();
    const int cc = blockIdx.x * 32 + ty;
#pragma unroll
    for (int i = 0; i < 4; ++i)
        dst[(size_t)(cc + i * 8) * pitch + r0 + tx] = f2b(t[tx][ty + i * 8]);
}

// ---------------------------------------------------------------------------
// bf16 MFMA GEMM, B^T input: C[M][N] = A[M][K] @ Bt[N][K]^T
// 128x128 tile, BK=32, 256 threads (4 waves, 2x2), 16x16x32 MFMA.
// MODE 0: plain fp32 store to Cf[M][N]
// MODE 1: fused QKV epilogue (block-uniform routing by n0):
//         n<1024  -> qh[m][n]          = bf16(tanh)
//         n<1280  -> kh[m][n-1024]     = bf16(tanh)
//         else    -> vtt[(b*4+g)*64+v][s] = bf16(sigmoid)   (V transposed)
// ---------------------------------------------------------------------------
template <int MODE>
__global__ __launch_bounds__(256) void gemm_bt_mfma(
    const unsigned short* __restrict__ A,
    const unsigned short* __restrict__ Bt,
    int M, int N, int K,
    float* __restrict__ Cf,
    unsigned short* __restrict__ qh,
    unsigned short* __restrict__ kh,
    unsigned short* __restrict__ vtt)
{
    __shared__ __align__(16) unsigned short As[128][40];   // pitch 40 bf16 = 80B (16B mult)
    __shared__ __align__(16) unsigned short Bs[128][40];

    const int tid = threadIdx.x;
    const int w = tid >> 6, lane = tid & 63, l15 = lane & 15, quad = lane >> 4;
    const int wm = w & 1, wn = w >> 1;
    const int m0 = blockIdx.y * 128, n0 = blockIdx.x * 128;

    f32x4 acc[4][4];
    const f32x4 zero4 = {0.f, 0.f, 0.f, 0.f};
#pragma unroll
    for (int i = 0; i < 4; ++i)
#pragma unroll
        for (int j = 0; j < 4; ++j) acc[i][j] = zero4;

    const int r0 = tid >> 2, oo = (tid & 3) * 8;   // chunk row / k-offset
    const int r1 = r0 + 64;

    for (int k0 = 0; k0 < K; k0 += 32) {
        uint4 a0 = *(const uint4*)(A  + (size_t)(m0 + r0) * K + k0 + oo);
        uint4 a1 = *(const uint4*)(A  + (size_t)(m0 + r1) * K + k0 + oo);
        uint4 b0 = *(const uint4*)(Bt + (size_t)(n0 + r0) * K + k0 + oo);
        uint4 b1 = *(const uint4*)(Bt + (size_t)(n0 + r1) * K + k0 + oo);
        __syncthreads();
        *(uint4*)&As[r0][oo] = a0;
        *(uint4*)&As[r1][oo] = a1;
        *(uint4*)&Bs[r0][oo] = b0;
        *(uint4*)&Bs[r1][oo] = b1;
        __syncthreads();

        bf16x8 af[4], bf[4];
#pragma unroll
        for (int t = 0; t < 4; ++t) af[t] = *(const bf16x8*)&As[wm * 64 + t * 16 + l15][quad * 8];
#pragma unroll
        for (int t = 0; t < 4; ++t) bf[t] = *(const bf16x8*)&Bs[wn * 64 + t * 16 + l15][quad * 8];
#pragma unroll
        for (int mt = 0; mt < 4; ++mt)
#pragma unroll
            for (int nt = 0; nt < 4; ++nt)
                acc[mt][nt] = MFMA_BF16(af[mt], bf[nt], acc[mt][nt]);
    }

    // epilogue: C/D layout col = l15 (+16*nt), row = quad*4 + r (+16*mt)
    if (MODE == 0) {
#pragma unroll
        for (int mt = 0; mt < 4; ++mt)
#pragma unroll
            for (int nt = 0; nt < 4; ++nt) {
                const int gn = n0 + wn * 64 + nt * 16 + l15;
#pragma unroll
                for (int r = 0; r < 4; ++r) {
                    const int gm = m0 + wm * 64 + mt * 16 + quad * 4 + r;
                    Cf[(size_t)gm * N + gn] = acc[mt][nt][r];
                }
            }
    } else {
        if (n0 < 1024) {            // Q: tanh -> qh[m][n], pitch 1024
#pragma unroll
            for (int mt = 0; mt < 4; ++mt)
#pragma unroll
                for (int nt = 0; nt < 4; ++nt) {
                    const int gn = n0 + wn * 64 + nt * 16 + l15;
#pragma unroll
                    for (int r = 0; r < 4; ++r) {
                        const int gm = m0 + wm * 64 + mt * 16 + quad * 4 + r;
                        qh[(size_t)gm * 1024 + gn] = f2b(tanhf(acc[mt][nt][r]));
                    }
                }
        } else if (n0 < 1280) {     // K: tanh -> kh[m][n-1024], pitch 256
#pragma unroll
            for (int mt = 0; mt < 4; ++mt)
#pragma unroll
                for (int nt = 0; nt < 4; ++nt) {
                    const int gn = n0 + wn * 64 + nt * 16 + l15 - 1024;
#pragma unroll
                    for (int r = 0; r < 4; ++r) {
                        const int gm = m0 + wm * 64 + mt * 16 + quad * 4 + r;
                        kh[(size_t)gm * 256 + gn] = f2b(tanhf(acc[mt][nt][r]));
                    }
                }
        } else {                    // V: sigmoid -> vtt[(b*4+g)*64+v][s] (transposed)
#pragma unroll
            for (int mt = 0; mt < 4; ++mt)
#pragma unroll
                for (int nt = 0; nt < 4; ++nt) {
                    const int gn = n0 + wn * 64 + nt * 16 + l15 - 1280;
                    const int g = gn >> 6, vv = gn & 63;
                    const int s0 = m0 + wm * 64 + mt * 16 + quad * 4;   // 4 consecutive s
                    const int b = s0 >> 11, sl = s0 & 2047;
                    ushort4 pk;
                    unsigned short* pp = (unsigned short*)&pk;
#pragma unroll
                    for (int r = 0; r < 4; ++r) {
                        float sv = 1.0f / (1.0f + __expf(-acc[mt][nt][r]));
                        pp[r] = f2b(sv);
                    }
                    *(ushort4*)&vtt[((size_t)(b * 4 + g) * 64 + vv) * 2048 + sl] = pk;
                }
        }
    }
}

// ---------------------------------------------------------------------------
// MFMA flash attention. Block = (pair, h, b): processes q-tiles `pair` and
// `31-pair` (uniform 33 k-tiles total). 4 waves; wave w owns q-rows w*16..+15.
// qh [b,s,h,64] bf16, kh [b,s,g,64] bf16, vtt [b,g,v,s] bf16 (transposed).
// P round-trips through LDS (C-layout -> A-operand layout).
// Epilogue fuses out_bits = e0 + ctx*(e1-e0), writes bf16 ob [b,s,h,64].
// ---------------------------------------------------------------------------
__global__ __launch_bounds__(256) void rosa_attn_mfma(
    const unsigned short* __restrict__ qh,
    const unsigned short* __restrict__ kh,
    const unsigned short* __restrict__ vtt,
    const int* __restrict__ amask,
    const float* __restrict__ emb0,
    const float* __restrict__ emb1,
    unsigned short* __restrict__ ob)
{
    __shared__ __align__(16) unsigned short Qs[64][72];   // pitch 72 bf16 = 144B
    __shared__ __align__(16) unsigned short Ks[64][72];
    __shared__ __align__(16) unsigned short Vts[64][72];  // [v][j]
    __shared__ __align__(16) unsigned short Ps[64][72];   // [q][j]
    __shared__ float Msf[64];

    const int pairI = blockIdx.x;                 // 0..15
    const int h = blockIdx.y, b = blockIdx.z, g = h >> 2;
    const int tid = threadIdx.x;
    const int w = tid >> 6, lane = tid & 63, l15 = lane & 15, quad = lane >> 4;

    float e0v[4], e1v[4];
#pragma unroll
    for (int nt = 0; nt < 4; ++nt) {
        e0v[nt] = emb0[h * 64 + nt * 16 + l15];
        e1v[nt] = emb1[h * 64 + nt * 16 + l15];
    }

    const f32x4 zero4 = {0.f, 0.f, 0.f, 0.f};

    for (int half = 0; half < 2; ++half) {
        const int qt = (half == 0) ? pairI : 31 - pairI;
        const int q0 = qt * 64;

        __syncthreads();
        for (int c = tid; c < 512; c += 256) {
            const int row = c >> 3, off = (c & 7) * 8;
            *(uint4*)&Qs[row][off] =
                *(const uint4*)&qh[((size_t)(b * 2048 + q0 + row) * 16 + h) * 64 + off];
        }
        __syncthreads();

        const bf16x8 qf0 = *(const bf16x8*)&Qs[w * 16 + l15][quad * 8];
        const bf16x8 qf1 = *(const bf16x8*)&Qs[w * 16 + l15][32 + quad * 8];

        float m_r[4], l_r[4];
        f32x4 oacc[4];
#pragma unroll
        for (int r = 0; r < 4; ++r) { m_r[r] = -1e30f; l_r[r] = 0.f; }
#pragma unroll
        for (int t = 0; t < 4; ++t) oacc[t] = zero4;

        const int qrow_base = q0 + w * 16 + quad * 4;

        for (int kt = 0; kt <= qt; ++kt) {
            const int k0 = kt * 64;
            __syncthreads();
            for (int c = tid; c < 512; c += 256) {
                const int row = c >> 3, off = (c & 7) * 8;
                *(uint4*)&Ks[row][off] =
                    *(const uint4*)&kh[((size_t)(b * 2048 + k0 + row) * 4 + g) * 64 + off];
                *(uint4*)&Vts[row][off] =
                    *(const uint4*)&vtt[((size_t)(b * 4 + g) * 64 + row) * 2048 + k0 + off];
            }
            if (tid < 64) Msf[tid] = amask[b * 2048 + k0 + tid] ? 1.0f : 0.0f;
            __syncthreads();

            // S = Q K^T  (A = Q[q][d], B[d][kidx] = K[kidx][d] read from Ks rows)
            f32x4 sc[4];
#pragma unroll
            for (int t = 0; t < 4; ++t) sc[t] = zero4;
#pragma unroll
            for (int nt = 0; nt < 4; ++nt) {
                bf16x8 kf = *(const bf16x8*)&Ks[nt * 16 + l15][quad * 8];
                sc[nt] = MFMA_BF16(qf0, kf, sc[nt]);
            }
#pragma unroll
            for (int nt = 0; nt < 4; ++nt) {
                bf16x8 kf = *(const bf16x8*)&Ks[nt * 16 + l15][32 + quad * 8];
                sc[nt] = MFMA_BF16(qf1, kf, sc[nt]);
            }

            // scale + mask + online softmax (rows = quad*4+r, cols = nt*16+l15)
            float mrow[4];
#pragma unroll
            for (int r = 0; r < 4; ++r) mrow[r] = -1e30f;
#pragma unroll
            for (int nt = 0; nt < 4; ++nt) {
                const int kg = k0 + nt * 16 + l15;
                const float mk = Msf[nt * 16 + l15];
#pragma unroll
                for (int r = 0; r < 4; ++r) {
                    float sv = sc[nt][r] * 0.015625f;   // /64
                    const bool valid = (kg <= qrow_base + r) && (mk != 0.0f);
                    sv = valid ? sv : -1e30f;
                    sc[nt][r] = sv;
                    mrow[r] = fmaxf(mrow[r], sv);
                }
            }
#pragma unroll
            for (int r = 0; r < 4; ++r) {
                mrow[r] = fmaxf(mrow[r], __shfl_xor(mrow[r], 1));
                mrow[r] = fmaxf(mrow[r], __shfl_xor(mrow[r], 2));
                mrow[r] = fmaxf(mrow[r], __shfl_xor(mrow[r], 4));
                mrow[r] = fmaxf(mrow[r], __shfl_xor(mrow[r], 8));
            }
            float alpha[4], psum[4];
#pragma unroll
            for (int r = 0; r < 4; ++r) {
                const float mn = fmaxf(m_r[r], mrow[r]);
                alpha[r] = __expf(m_r[r] - mn);
                m_r[r] = mn;
                psum[r] = 0.f;
            }
#pragma unroll
            for (int nt = 0; nt < 4; ++nt)
#pragma unroll
                for (int r = 0; r < 4; ++r) {
                    const float p = __expf(sc[nt][r] - m_r[r]);
                    psum[r] += p;
                    sc[nt][r] = p;
                }
#pragma unroll
            for (int r = 0; r < 4; ++r) {
                psum[r] += __shfl_xor(psum[r], 1);
                psum[r] += __shfl_xor(psum[r], 2);
                psum[r] += __shfl_xor(psum[r], 4);
                psum[r] += __shfl_xor(psum[r], 8);
                l_r[r] = l_r[r] * alpha[r] + psum[r];
            }

            // P -> LDS (wave-exclusive rows w*16..w*16+15; in-wave DS ordering)
#pragma unroll
            for (int nt = 0; nt < 4; ++nt)
#pragma unroll
                for (int r = 0; r < 4; ++r)
                    Ps[w * 16 + quad * 4 + r][nt * 16 + l15] = f2b(sc[nt][r]);

#pragma unroll
            for (int t = 0; t < 4; ++t) {
                oacc[t][0] *= alpha[0]; oacc[t][1] *= alpha[1];
                oacc[t][2] *= alpha[2]; oacc[t][3] *= alpha[3];
            }

            // O += P V   (A = P[q][j] from Ps, B[j][v] = Vts[v][j] rows)
            const bf16x8 pf0 = *(const bf16x8*)&Ps[w * 16 + l15][quad * 8];
            const bf16x8 pf1 = *(const bf16x8*)&Ps[w * 16 + l15][32 + quad * 8];
#pragma unroll
            for (int nt = 0; nt < 4; ++nt) {
                bf16x8 vf = *(const bf16x8*)&Vts[nt * 16 + l15][quad * 8];
                oacc[nt] = MFMA_BF16(pf0, vf, oacc[nt]);
            }
#pragma unroll
            for (int nt = 0; nt < 4; ++nt) {
                bf16x8 vf = *(const bf16x8*)&Vts[nt * 16 + l15][32 + quad * 8];
                oacc[nt] = MFMA_BF16(pf1, vf, oacc[nt]);
            }
        }

        // epilogue: out_bits = e0 + (o/l)*(e1-e0) -> ob bf16
        float invl[4];
#pragma unroll
        for (int r = 0; r < 4; ++r) invl[r] = 1.0f / l_r[r];
#pragma unroll
        for (int nt = 0; nt < 4; ++nt)
#pragma unroll
            for (int r = 0; r < 4; ++r) {
                const float ctx = oacc[nt][r] * invl[r];
                const float val = e0v[nt] + ctx * (e1v[nt] - e0v[nt]);
                const size_t s_idx = (size_t)(b * 2048 + q0 + w * 16 + quad * 4 + r);
                ob[(s_idx * 16 + h) * 64 + nt * 16 + l15] = f2b(val);
            }
    }
}

// ---------------------------------------------------------------------------
extern "C" void kernel_launch(void* const* d_in, const int* in_sizes, int n_in,
                              void* d_out, int out_size, void* d_ws, size_t ws_size,
                              hipStream_t stream)
{
    const float* x    = (const float*)d_in[0];
    const int*   amask= (const int*)d_in[1];
    const float* Wq   = (const float*)d_in[2];
    const float* Wk   = (const float*)d_in[3];
    const float* Wv   = (const float*)d_in[4];
    const float* Wo   = (const float*)d_in[5];
    const float* emb0 = (const float*)d_in[6];
    const float* emb1 = (const float*)d_in[7];
    float* out = (float*)d_out;

    // workspace layout (38 MB total; ob aliases dead xh):
    char* base = (char*)d_ws;
    unsigned short* xh    = (unsigned short*)(base);                      // 16 MB
    unsigned short* ob    = xh;                                           // aliases xh
    unsigned short* Wqkvt = (unsigned short*)(base + (22u << 20) - (6u << 20)); // 16 MB off
    unsigned short* Wot   = (unsigned short*)(base + (22u << 20));        // 4 MB
    unsigned short* qh    = (unsigned short*)(base + (26u << 20));        // 8 MB
    unsigned short* kh    = (unsigned short*)(base + (34u << 20));        // 2 MB
    unsigned short* vtt   = (unsigned short*)(base + (36u << 20));        // 2 MB

    conv_bf16<<<2048, 256, 0, stream>>>(x, xh, 4096 * 2048);
    transp_conv<<<dim3(1024 / 32, 2048 / 32), dim3(32, 8), 0, stream>>>(Wq, 2048, 1024, Wqkvt, 2048);
    transp_conv<<<dim3(256 / 32, 2048 / 32), dim3(32, 8), 0, stream>>>(Wk, 2048, 256, Wqkvt + (size_t)1024 * 2048, 2048);
    transp_conv<<<dim3(256 / 32, 2048 / 32), dim3(32, 8), 0, stream>>>(Wv, 2048, 256, Wqkvt + (size_t)1280 * 2048, 2048);
    transp_conv<<<dim3(2048 / 32, 1024 / 32), dim3(32, 8), 0, stream>>>(Wo, 1024, 2048, Wot, 1024);

    gemm_bt_mfma<1><<<dim3(12, 32), 256, 0, stream>>>(xh, Wqkvt, 4096, 1536, 2048,
                                                      nullptr, qh, kh, vtt);
    rosa_attn_mfma<<<dim3(16, 16, 2), 256, 0, stream>>>(qh, kh, vtt, amask, emb0, emb1, ob);
    gemm_bt_mfma<0><<<dim3(16, 32), 256, 0, stream>>>(ob, Wot, 4096, 2048, 1024,
                                                      out, nullptr, nullptr, nullptr);
}